// Round 5
// baseline (561.553 us; speedup 1.0000x reference)
//
#include <hip/hip_runtime.h>

#define NN 50000      // nodes
#define NE 600000     // edges
#define HC 128        // hidden channels
#define CHN 32        // chunk size
#define NG 64         // graphs
#define LN_EPS 1e-5f

// ---------------- CSR build ----------------

__global__ void __launch_bounds__(256) k_hist(const int* __restrict__ ei, int* __restrict__ cnt) {
    int e = blockIdx.x * 256 + threadIdx.x;
    if (e >= NE) return;
    int s = ei[e], d = ei[NE + e];
    if (s != d) atomicAdd(&cnt[d], 1);
}

// ---- 3-phase device-wide exclusive scan of cnt[NN] -> row_ptr[NN+1] ----
#define SC_BLOCKS 49   // ceil(50000/1024)

__global__ void __launch_bounds__(256) k_scanA(const int* __restrict__ cnt, int* __restrict__ blocksum) {
    int b = blockIdx.x, t = threadIdx.x;
    int idx = b * 1024 + t * 4;
    int4 v = make_int4(0, 0, 0, 0);
    if (idx + 3 < NN) v = *(const int4*)&cnt[idx];
    else {
        if (idx + 0 < NN) v.x = cnt[idx + 0];
        if (idx + 1 < NN) v.y = cnt[idx + 1];
        if (idx + 2 < NN) v.z = cnt[idx + 2];
        if (idx + 3 < NN) v.w = cnt[idx + 3];
    }
    int s = v.x + v.y + v.z + v.w;
    for (int m = 1; m < 64; m <<= 1) s += __shfl_xor(s, m, 64);
    __shared__ int ws[4];
    if ((t & 63) == 0) ws[t >> 6] = s;
    __syncthreads();
    if (t == 0) blocksum[b] = ws[0] + ws[1] + ws[2] + ws[3];
}

__global__ void __launch_bounds__(64) k_scanB(const int* __restrict__ blocksum, int* __restrict__ blockoff) {
    int t = threadIdx.x;
    int v = (t < SC_BLOCKS) ? blocksum[t] : 0;
    int inc = v;
    for (int d = 1; d < 64; d <<= 1) { int u = __shfl_up(inc, d, 64); if (t >= d) inc += u; }
    if (t < SC_BLOCKS) blockoff[t + 1] = inc;
    if (t == 0) blockoff[0] = 0;
}

__global__ void __launch_bounds__(256) k_scanC(const int* __restrict__ cnt, const int* __restrict__ blockoff,
                                               int* __restrict__ row_ptr) {
    int b = blockIdx.x, t = threadIdx.x;
    int idx = b * 1024 + t * 4;
    int4 v = make_int4(0, 0, 0, 0);
    if (idx + 3 < NN) v = *(const int4*)&cnt[idx];
    else {
        if (idx + 0 < NN) v.x = cnt[idx + 0];
        if (idx + 1 < NN) v.y = cnt[idx + 1];
        if (idx + 2 < NN) v.z = cnt[idx + 2];
        if (idx + 3 < NN) v.w = cnt[idx + 3];
    }
    int s = v.x + v.y + v.z + v.w;
    int lane = t & 63, w = t >> 6;
    int inc = s;
    for (int d = 1; d < 64; d <<= 1) { int u = __shfl_up(inc, d, 64); if (lane >= d) inc += u; }
    __shared__ int wsum[4];
    if (lane == 63) wsum[w] = inc;
    __syncthreads();
    int off = blockoff[b];
    for (int i = 0; i < w; ++i) off += wsum[i];
    int excl = off + inc - s;
    if (idx + 0 < NN) row_ptr[idx + 0] = excl;
    if (idx + 1 < NN) row_ptr[idx + 1] = excl + v.x;
    if (idx + 2 < NN) row_ptr[idx + 2] = excl + v.x + v.y;
    if (idx + 3 < NN) row_ptr[idx + 3] = excl + v.x + v.y + v.z;
    if (b == 0 && t == 0) row_ptr[NN] = blockoff[SC_BLOCKS];
}

__global__ void __launch_bounds__(256) k_fill(const int* __restrict__ ei, const int* __restrict__ row_ptr,
                                              int* __restrict__ fill, int* __restrict__ col) {
    int e = blockIdx.x * 256 + threadIdx.x;
    if (e >= NE) return;
    int s = ei[e], d = ei[NE + e];
    if (s != d) {
        int pos = atomicAdd(&fill[d], 1);
        col[row_ptr[d] + pos] = s;
    }
}

// ---------------- input MLP: h = LN(relu(x @ W_in + b_in)) ----------------

#define MLP_NB 8
#define MLP_GROUPS (NN / MLP_NB)   // 6250, exact

__global__ void __launch_bounds__(256) k_mlp(const float* __restrict__ x, const float* __restrict__ W,
                                             const float* __restrict__ b, const float* __restrict__ g,
                                             const float* __restrict__ be, float* __restrict__ h) {
    __shared__ float Ws[HC][HC];            // 64 KB
    __shared__ float xs[4][MLP_NB][HC];     // 16 KB
    int tid = threadIdx.x;
    for (int i = tid * 4; i < HC * HC; i += 256 * 4) {
        *(float4*)&((float*)Ws)[i] = *(const float4*)&W[i];
    }
    __syncthreads();
    int wave = tid >> 6, lane = tid & 63;
    float bx = b[2 * lane],  by = b[2 * lane + 1];
    float gx = g[2 * lane],  gy = g[2 * lane + 1];
    float bex = be[2 * lane], bey = be[2 * lane + 1];
    for (int grp = blockIdx.x * 4 + wave; grp < MLP_GROUPS; grp += gridDim.x * 4) {
        int base = grp * MLP_NB;
        #pragma unroll
        for (int nb = 0; nb < MLP_NB; ++nb) {
            float2 xv = *(const float2*)&x[(size_t)(base + nb) * HC + 2 * lane];
            *(float2*)&xs[wave][nb][2 * lane] = xv;
        }
        float ax[MLP_NB], ay[MLP_NB];
        #pragma unroll
        for (int nb = 0; nb < MLP_NB; ++nb) { ax[nb] = bx; ay[nb] = by; }
        for (int c = 0; c < HC; c += 4) {
            float2 wv0 = *(const float2*)&Ws[c + 0][2 * lane];
            float2 wv1 = *(const float2*)&Ws[c + 1][2 * lane];
            float2 wv2 = *(const float2*)&Ws[c + 2][2 * lane];
            float2 wv3 = *(const float2*)&Ws[c + 3][2 * lane];
            #pragma unroll
            for (int nb = 0; nb < MLP_NB; ++nb) {
                float4 xv = *(const float4*)&xs[wave][nb][c];
                ax[nb] = fmaf(xv.x, wv0.x, ax[nb]); ay[nb] = fmaf(xv.x, wv0.y, ay[nb]);
                ax[nb] = fmaf(xv.y, wv1.x, ax[nb]); ay[nb] = fmaf(xv.y, wv1.y, ay[nb]);
                ax[nb] = fmaf(xv.z, wv2.x, ax[nb]); ay[nb] = fmaf(xv.z, wv2.y, ay[nb]);
                ax[nb] = fmaf(xv.w, wv3.x, ax[nb]); ay[nb] = fmaf(xv.w, wv3.y, ay[nb]);
            }
        }
        #pragma unroll
        for (int nb = 0; nb < MLP_NB; ++nb) {
            float a0 = fmaxf(ax[nb], 0.f), a1 = fmaxf(ay[nb], 0.f);
            float sm = a0 + a1;
            for (int m = 1; m < 64; m <<= 1) sm += __shfl_xor(sm, m, 64);
            float mu = sm * (1.f / 128.f);
            float d0 = a0 - mu, d1 = a1 - mu;
            float vv = d0 * d0 + d1 * d1;
            for (int m = 1; m < 64; m <<= 1) vv += __shfl_xor(vv, m, 64);
            float inv = rsqrtf(vv * (1.f / 128.f) + LN_EPS);
            float2 o;
            o.x = d0 * inv * gx + bex;
            o.y = d1 * inv * gy + bey;
            *(float2*)&h[(size_t)(base + nb) * HC + 2 * lane] = o;
        }
    }
}

// ---------------- fused layer: gather-sum + mean + gating + mix + LN ----------------
// One wave per node. Reads h_in (prev layer, never written here), writes h_out.
// deg = (r1-r0) + 1 (valid in-edges + self loop). tm read/write is per-node-private.

__global__ void __launch_bounds__(256) k_layer(const float* __restrict__ h_in, float* __restrict__ h_out,
        const int* __restrict__ row_ptr, const int* __restrict__ col,
        const float* __restrict__ Wtm, const float* __restrict__ btm,
        const float* __restrict__ gall, const float* __restrict__ ball,
        float* __restrict__ tm, int layer) {
    __shared__ float Ws[2 * HC * CHN];   // 32 KB, [256][32] row-major
    __shared__ float bs[CHN];
    __shared__ float gs[HC], bes[HC];
    __shared__ float hs[4][HC], ms[4][HC];
    int tid = threadIdx.x;
    for (int i = tid; i < 2 * HC * CHN; i += 256) Ws[i] = Wtm[i];
    if (tid < CHN) bs[tid] = btm[tid];
    if (tid < HC) { gs[tid] = gall[layer * HC + tid]; bes[tid] = ball[layer * HC + tid]; }
    __syncthreads();
    int wave = tid >> 6, lane = tid & 63;
    int k = lane & 31, half = lane >> 5;
    for (int node = blockIdx.x * 4 + wave; node < NN; node += gridDim.x * 4) {
        int r0 = row_ptr[node], r1 = row_ptr[node + 1];
        float ax = 0.f, ay = 0.f;
        for (int j = r0; j < r1; ++j) {
            int s = col[j];
            float2 hv = *(const float2*)&h_in[(size_t)s * HC + 2 * lane];
            ax += hv.x; ay += hv.y;
        }
        float2 hv = *(const float2*)&h_in[(size_t)node * HC + 2 * lane];
        float invdeg = 1.f / (float)(r1 - r0 + 1);
        float2 mv;
        mv.x = (ax + hv.x) * invdeg;
        mv.y = (ay + hv.y) * invdeg;
        hs[wave][2 * lane] = hv.x; hs[wave][2 * lane + 1] = hv.y;
        ms[wave][2 * lane] = mv.x; ms[wave][2 * lane + 1] = mv.y;
        // wave-local LDS only: compiler inserts the lgkmcnt wait; no block barrier needed
        const float* src = half ? ms[wave] : hs[wave];
        const float* Wr  = &Ws[half * HC * CHN];
        float z = 0.f;
        for (int c = 0; c < HC; ++c) z = fmaf(src[c], Wr[c * CHN + k], z);
        z += __shfl_xor(z, 32, 64);      // combine the two K-halves
        z += bs[k];
        // softmax over the 32 gates (width-32 ops: both halves identical)
        float mx = z;
        for (int m = 1; m < 32; m <<= 1) mx = fmaxf(mx, __shfl_xor(mx, m, 32));
        float e = expf(z - mx);
        float se = e;
        for (int m = 1; m < 32; m <<= 1) se += __shfl_xor(se, m, 32);
        float p = e / se;
        // inclusive cumsum over gate index k
        float cum = p;
        for (int d = 1; d < 32; d <<= 1) {
            float t2 = __shfl_up(cum, d, 32);
            if (k >= d) cum += t2;
        }
        float tmo = tm[(size_t)node * CHN + k];
        float raw = tmo + (1.f - tmo) * cum;
        if (half == 0) tm[(size_t)node * CHN + k] = raw;
        // sig for channels (2*lane, 2*lane+1): both in gate group lane>>1
        float sig = __shfl(raw, lane >> 1, 64);
        float v0 = hv.x * sig + mv.x * (1.f - sig);
        float v1 = hv.y * sig + mv.y * (1.f - sig);
        float sm = v0 + v1;
        for (int m = 1; m < 64; m <<= 1) sm += __shfl_xor(sm, m, 64);
        float mu = sm * (1.f / 128.f);
        float d0 = v0 - mu, d1 = v1 - mu;
        float vv = d0 * d0 + d1 * d1;
        for (int m = 1; m < 64; m <<= 1) vv += __shfl_xor(vv, m, 64);
        float inv = rsqrtf(vv * (1.f / 128.f) + LN_EPS);
        float2 o;
        o.x = d0 * inv * gs[2 * lane]     + bes[2 * lane];
        o.y = d1 * inv * gs[2 * lane + 1] + bes[2 * lane + 1];
        *(float2*)&h_out[(size_t)node * HC + 2 * lane] = o;
    }
}

// ---------------- global mean pool (batch is sorted) ----------------

__global__ void __launch_bounds__(1024) k_pool(const float* __restrict__ h, const int* __restrict__ batch,
                                               float* __restrict__ out) {
    __shared__ float red[8][HC];
    int g = blockIdx.x;
    int tid = threadIdx.x;
    int c = tid & (HC - 1);
    int w = tid >> 7;          // 0..7 node-slice
    int a = 0, bnd = NN;
    while (a < bnd) { int mid = (a + bnd) >> 1; if (batch[mid] < g) a = mid + 1; else bnd = mid; }
    int start = a;
    bnd = NN;
    while (a < bnd) { int mid = (a + bnd) >> 1; if (batch[mid] <= g) a = mid + 1; else bnd = mid; }
    int end = a;
    float acc = 0.f;
    for (int n = start + w; n < end; n += 8) acc += h[(size_t)n * HC + c];
    red[w][c] = acc;
    __syncthreads();
    if (w == 0) {
        float s = red[0][c] + red[1][c] + red[2][c] + red[3][c]
                + red[4][c] + red[5][c] + red[6][c] + red[7][c];
        int count = end - start;
        out[g * HC + c] = s / (float)max(count, 1);
    }
}

// ---------------- launch ----------------

extern "C" void kernel_launch(void* const* d_in, const int* in_sizes, int n_in,
                              void* d_out, int out_size, void* d_ws, size_t ws_size,
                              hipStream_t stream) {
    const float* x     = (const float*)d_in[0];
    const int*   ei    = (const int*)d_in[1];
    const int*   batch = (const int*)d_in[2];
    const float* W_in  = (const float*)d_in[3];
    const float* b_in  = (const float*)d_in[4];
    const float* g_in  = (const float*)d_in[5];
    const float* be_in = (const float*)d_in[6];
    const float* W_tm  = (const float*)d_in[7];
    const float* b_tm  = (const float*)d_in[8];
    const float* tm_g  = (const float*)d_in[9];
    const float* tm_b  = (const float*)d_in[10];
    float* out = (float*)d_out;

    char* ws = (char*)d_ws;
    int*   cnt = (int*)(ws + 0);              // NN ints
    int*   fil = (int*)(ws + 200000);         // NN ints
    int*   rp  = (int*)(ws + 400000);         // NN+1 ints
    int*   col = (int*)(ws + 600004);         // NE ints   (ends at 3,000,004)
    float* hA  = (float*)(ws + 3000064);      // NN*HC floats (25.6 MB)
    float* hB  = (float*)(ws + 28600064);     // NN*HC floats (ping-pong)
    float* tm  = (float*)(ws + 54200064);     // NN*CHN floats (6.4 MB)
    int*   bsum = (int*)(ws + 60600064);      // SC_BLOCKS ints
    int*   boff = (int*)(ws + 60600320);      // SC_BLOCKS+1 ints

    hipMemsetAsync(cnt, 0, 400000, stream);       // cnt + fil (contiguous)
    hipMemsetAsync(tm, 0, 6400000, stream);       // last_tm_signal = 0

    k_hist<<<(NE + 255) / 256, 256, 0, stream>>>(ei, cnt);
    k_scanA<<<SC_BLOCKS, 256, 0, stream>>>(cnt, bsum);
    k_scanB<<<1, 64, 0, stream>>>(bsum, boff);
    k_scanC<<<SC_BLOCKS, 256, 0, stream>>>(cnt, boff, rp);
    k_fill<<<(NE + 255) / 256, 256, 0, stream>>>(ei, rp, fil, col);

    k_mlp<<<392, 256, 0, stream>>>(x, W_in, b_in, g_in, be_in, hA);

    // ping-pong: layer j reads buf[j%2], writes buf[(j+1)%2]
    k_layer<<<1024, 256, 0, stream>>>(hA, hB, rp, col, W_tm, b_tm, tm_g, tm_b, tm, 0);
    k_layer<<<1024, 256, 0, stream>>>(hB, hA, rp, col, W_tm, b_tm, tm_g, tm_b, tm, 1);
    k_layer<<<1024, 256, 0, stream>>>(hA, hB, rp, col, W_tm, b_tm, tm_g, tm_b, tm, 2);

    k_pool<<<NG, 1024, 0, stream>>>(hB, batch, out);
}

// Round 6
// 523.294 us; speedup vs baseline: 1.0731x; 1.0731x over previous
//
#include <hip/hip_runtime.h>

#define NN 50000      // nodes
#define NE 600000     // edges
#define HC 128        // hidden channels
#define CHN 32        // chunk size
#define NG 64         // graphs
#define LN_EPS 1e-5f

typedef unsigned short ushort_t;
typedef unsigned int uint_t;

__device__ __forceinline__ ushort_t f2bf(float f) {   // RNE round to bf16
    uint_t u = __builtin_bit_cast(uint_t, f);
    u = (u + 0x7FFFu + ((u >> 16) & 1u)) >> 16;
    return (ushort_t)u;
}
__device__ __forceinline__ float bf2f(ushort_t s) {
    uint_t u = (uint_t)s << 16;
    return __builtin_bit_cast(float, u);
}

// ---------------- CSR build ----------------

__global__ void __launch_bounds__(256) k_hist(const int* __restrict__ ei, int* __restrict__ cnt) {
    int e = blockIdx.x * 256 + threadIdx.x;
    if (e >= NE) return;
    int s = ei[e], d = ei[NE + e];
    if (s != d) atomicAdd(&cnt[d], 1);
}

// ---- 3-phase device-wide exclusive scan of cnt[NN] -> row_ptr[NN+1] ----
#define SC_BLOCKS 49   // ceil(50000/1024)

__global__ void __launch_bounds__(256) k_scanA(const int* __restrict__ cnt, int* __restrict__ blocksum) {
    int b = blockIdx.x, t = threadIdx.x;
    int idx = b * 1024 + t * 4;
    int4 v = make_int4(0, 0, 0, 0);
    if (idx + 3 < NN) v = *(const int4*)&cnt[idx];
    else {
        if (idx + 0 < NN) v.x = cnt[idx + 0];
        if (idx + 1 < NN) v.y = cnt[idx + 1];
        if (idx + 2 < NN) v.z = cnt[idx + 2];
        if (idx + 3 < NN) v.w = cnt[idx + 3];
    }
    int s = v.x + v.y + v.z + v.w;
    for (int m = 1; m < 64; m <<= 1) s += __shfl_xor(s, m, 64);
    __shared__ int ws[4];
    if ((t & 63) == 0) ws[t >> 6] = s;
    __syncthreads();
    if (t == 0) blocksum[b] = ws[0] + ws[1] + ws[2] + ws[3];
}

__global__ void __launch_bounds__(64) k_scanB(const int* __restrict__ blocksum, int* __restrict__ blockoff) {
    int t = threadIdx.x;
    int v = (t < SC_BLOCKS) ? blocksum[t] : 0;
    int inc = v;
    for (int d = 1; d < 64; d <<= 1) { int u = __shfl_up(inc, d, 64); if (t >= d) inc += u; }
    if (t < SC_BLOCKS) blockoff[t + 1] = inc;
    if (t == 0) blockoff[0] = 0;
}

__global__ void __launch_bounds__(256) k_scanC(const int* __restrict__ cnt, const int* __restrict__ blockoff,
                                               int* __restrict__ row_ptr) {
    int b = blockIdx.x, t = threadIdx.x;
    int idx = b * 1024 + t * 4;
    int4 v = make_int4(0, 0, 0, 0);
    if (idx + 3 < NN) v = *(const int4*)&cnt[idx];
    else {
        if (idx + 0 < NN) v.x = cnt[idx + 0];
        if (idx + 1 < NN) v.y = cnt[idx + 1];
        if (idx + 2 < NN) v.z = cnt[idx + 2];
        if (idx + 3 < NN) v.w = cnt[idx + 3];
    }
    int s = v.x + v.y + v.z + v.w;
    int lane = t & 63, w = t >> 6;
    int inc = s;
    for (int d = 1; d < 64; d <<= 1) { int u = __shfl_up(inc, d, 64); if (lane >= d) inc += u; }
    __shared__ int wsum[4];
    if (lane == 63) wsum[w] = inc;
    __syncthreads();
    int off = blockoff[b];
    for (int i = 0; i < w; ++i) off += wsum[i];
    int excl = off + inc - s;
    if (idx + 0 < NN) row_ptr[idx + 0] = excl;
    if (idx + 1 < NN) row_ptr[idx + 1] = excl + v.x;
    if (idx + 2 < NN) row_ptr[idx + 2] = excl + v.x + v.y;
    if (idx + 3 < NN) row_ptr[idx + 3] = excl + v.x + v.y + v.z;
    if (b == 0 && t == 0) row_ptr[NN] = blockoff[SC_BLOCKS];
}

__global__ void __launch_bounds__(256) k_fill(const int* __restrict__ ei, const int* __restrict__ row_ptr,
                                              int* __restrict__ fill, int* __restrict__ col) {
    int e = blockIdx.x * 256 + threadIdx.x;
    if (e >= NE) return;
    int s = ei[e], d = ei[NE + e];
    if (s != d) {
        int pos = atomicAdd(&fill[d], 1);
        col[row_ptr[d] + pos] = s;
    }
}

// ---------------- input MLP: h = LN(relu(x @ W_in + b_in)) ----------------
// writes fp32 h and a bf16 mirror h2 (gather source for k_agg)

#define MLP_NB 8
#define MLP_GROUPS (NN / MLP_NB)   // 6250, exact

__global__ void __launch_bounds__(256) k_mlp(const float* __restrict__ x, const float* __restrict__ W,
                                             const float* __restrict__ b, const float* __restrict__ g,
                                             const float* __restrict__ be, float* __restrict__ h,
                                             ushort_t* __restrict__ h2) {
    __shared__ float Ws[HC][HC];            // 64 KB
    __shared__ float xs[4][MLP_NB][HC];     // 16 KB
    int tid = threadIdx.x;
    for (int i = tid * 4; i < HC * HC; i += 256 * 4) {
        *(float4*)&((float*)Ws)[i] = *(const float4*)&W[i];
    }
    __syncthreads();
    int wave = tid >> 6, lane = tid & 63;
    float bx = b[2 * lane],  by = b[2 * lane + 1];
    float gx = g[2 * lane],  gy = g[2 * lane + 1];
    float bex = be[2 * lane], bey = be[2 * lane + 1];
    for (int grp = blockIdx.x * 4 + wave; grp < MLP_GROUPS; grp += gridDim.x * 4) {
        int base = grp * MLP_NB;
        #pragma unroll
        for (int nb = 0; nb < MLP_NB; ++nb) {
            float2 xv = *(const float2*)&x[(size_t)(base + nb) * HC + 2 * lane];
            *(float2*)&xs[wave][nb][2 * lane] = xv;
        }
        float ax[MLP_NB], ay[MLP_NB];
        #pragma unroll
        for (int nb = 0; nb < MLP_NB; ++nb) { ax[nb] = bx; ay[nb] = by; }
        for (int c = 0; c < HC; c += 4) {
            float2 wv0 = *(const float2*)&Ws[c + 0][2 * lane];
            float2 wv1 = *(const float2*)&Ws[c + 1][2 * lane];
            float2 wv2 = *(const float2*)&Ws[c + 2][2 * lane];
            float2 wv3 = *(const float2*)&Ws[c + 3][2 * lane];
            #pragma unroll
            for (int nb = 0; nb < MLP_NB; ++nb) {
                float4 xv = *(const float4*)&xs[wave][nb][c];
                ax[nb] = fmaf(xv.x, wv0.x, ax[nb]); ay[nb] = fmaf(xv.x, wv0.y, ay[nb]);
                ax[nb] = fmaf(xv.y, wv1.x, ax[nb]); ay[nb] = fmaf(xv.y, wv1.y, ay[nb]);
                ax[nb] = fmaf(xv.z, wv2.x, ax[nb]); ay[nb] = fmaf(xv.z, wv2.y, ay[nb]);
                ax[nb] = fmaf(xv.w, wv3.x, ax[nb]); ay[nb] = fmaf(xv.w, wv3.y, ay[nb]);
            }
        }
        #pragma unroll
        for (int nb = 0; nb < MLP_NB; ++nb) {
            float a0 = fmaxf(ax[nb], 0.f), a1 = fmaxf(ay[nb], 0.f);
            float sm = a0 + a1;
            for (int m = 1; m < 64; m <<= 1) sm += __shfl_xor(sm, m, 64);
            float mu = sm * (1.f / 128.f);
            float d0 = a0 - mu, d1 = a1 - mu;
            float vv = d0 * d0 + d1 * d1;
            for (int m = 1; m < 64; m <<= 1) vv += __shfl_xor(vv, m, 64);
            float inv = rsqrtf(vv * (1.f / 128.f) + LN_EPS);
            float2 o;
            o.x = d0 * inv * gx + bex;
            o.y = d1 * inv * gy + bey;
            *(float2*)&h[(size_t)(base + nb) * HC + 2 * lane] = o;
            ushort2 o2; o2.x = f2bf(o.x); o2.y = f2bf(o.y);
            *(ushort2*)&h2[(size_t)(base + nb) * HC + 2 * lane] = o2;
        }
    }
}

// ---------------- per-node CSR aggregation over bf16 mirror ----------------

__global__ void __launch_bounds__(256) k_agg(const ushort_t* __restrict__ h2, const int* __restrict__ row_ptr,
                                             const int* __restrict__ col, float* __restrict__ agg) {
    int wave = threadIdx.x >> 6, lane = threadIdx.x & 63;
    int node = blockIdx.x * 4 + wave;
    int r0 = row_ptr[node], r1 = row_ptr[node + 1];
    float ax = 0.f, ay = 0.f;
    for (int j = r0; j < r1; ++j) {
        int s = col[j];
        ushort2 hv = *(const ushort2*)&h2[(size_t)s * HC + 2 * lane];
        ax += bf2f(hv.x); ay += bf2f(hv.y);
    }
    float2 o; o.x = ax; o.y = ay;
    *(float2*)&agg[(size_t)node * HC + 2 * lane] = o;
}

// ---------------- fused node update (gating matmul + softmax + cumsum + mix + LN) ----------------

__global__ void __launch_bounds__(256) k_update(float* __restrict__ h, ushort_t* __restrict__ h2,
        const float* __restrict__ agg,
        const int* __restrict__ cnt, const float* __restrict__ Wtm, const float* __restrict__ btm,
        const float* __restrict__ gall, const float* __restrict__ ball, float* __restrict__ tm, int layer) {
    __shared__ float Ws[2 * HC * CHN];   // 32 KB, [256][32] row-major
    __shared__ float bs[CHN];
    __shared__ float gs[HC], bes[HC];
    __shared__ float hs[4][HC], ms[4][HC];
    int tid = threadIdx.x;
    for (int i = tid; i < 2 * HC * CHN; i += 256) Ws[i] = Wtm[i];
    if (tid < CHN) bs[tid] = btm[tid];
    if (tid < HC) { gs[tid] = gall[layer * HC + tid]; bes[tid] = ball[layer * HC + tid]; }
    __syncthreads();
    int wave = tid >> 6, lane = tid & 63;
    int k = lane & 31, half = lane >> 5;
    for (int node = blockIdx.x * 4 + wave; node < NN; node += gridDim.x * 4) {
        float2 hv = *(const float2*)&h[(size_t)node * HC + 2 * lane];
        float2 av = *(const float2*)&agg[(size_t)node * HC + 2 * lane];
        float invdeg = 1.f / (float)(cnt[node] + 1);
        float2 mv;
        mv.x = (av.x + hv.x) * invdeg;
        mv.y = (av.y + hv.y) * invdeg;
        hs[wave][2 * lane] = hv.x; hs[wave][2 * lane + 1] = hv.y;
        ms[wave][2 * lane] = mv.x; ms[wave][2 * lane + 1] = mv.y;
        // wave-local LDS only: compiler inserts the lgkmcnt wait; no block barrier needed
        const float* src = half ? ms[wave] : hs[wave];
        const float* Wr  = &Ws[half * HC * CHN];
        float z = 0.f;
        for (int c = 0; c < HC; ++c) z = fmaf(src[c], Wr[c * CHN + k], z);
        z += __shfl_xor(z, 32, 64);      // combine the two K-halves
        z += bs[k];
        // softmax over the 32 gates (width-32 ops: both halves identical)
        float mx = z;
        for (int m = 1; m < 32; m <<= 1) mx = fmaxf(mx, __shfl_xor(mx, m, 32));
        float e = expf(z - mx);
        float se = e;
        for (int m = 1; m < 32; m <<= 1) se += __shfl_xor(se, m, 32);
        float p = e / se;
        // inclusive cumsum over gate index k
        float cum = p;
        for (int d = 1; d < 32; d <<= 1) {
            float t2 = __shfl_up(cum, d, 32);
            if (k >= d) cum += t2;
        }
        float tmo = tm[(size_t)node * CHN + k];
        float raw = tmo + (1.f - tmo) * cum;
        if (half == 0) tm[(size_t)node * CHN + k] = raw;
        // sig for channels (2*lane, 2*lane+1): both in gate group lane>>1
        float sig = __shfl(raw, lane >> 1, 64);
        float v0 = hv.x * sig + mv.x * (1.f - sig);
        float v1 = hv.y * sig + mv.y * (1.f - sig);
        float sm = v0 + v1;
        for (int m = 1; m < 64; m <<= 1) sm += __shfl_xor(sm, m, 64);
        float mu = sm * (1.f / 128.f);
        float d0 = v0 - mu, d1 = v1 - mu;
        float vv = d0 * d0 + d1 * d1;
        for (int m = 1; m < 64; m <<= 1) vv += __shfl_xor(vv, m, 64);
        float inv = rsqrtf(vv * (1.f / 128.f) + LN_EPS);
        float2 o;
        o.x = d0 * inv * gs[2 * lane]     + bes[2 * lane];
        o.y = d1 * inv * gs[2 * lane + 1] + bes[2 * lane + 1];
        *(float2*)&h[(size_t)node * HC + 2 * lane] = o;
        ushort2 o2; o2.x = f2bf(o.x); o2.y = f2bf(o.y);
        *(ushort2*)&h2[(size_t)node * HC + 2 * lane] = o2;
    }
}

// ---------------- global mean pool (batch is sorted) ----------------

__global__ void __launch_bounds__(1024) k_pool(const float* __restrict__ h, const int* __restrict__ batch,
                                               float* __restrict__ out) {
    __shared__ float red[8][HC];
    int g = blockIdx.x;
    int tid = threadIdx.x;
    int c = tid & (HC - 1);
    int w = tid >> 7;          // 0..7 node-slice
    int a = 0, bnd = NN;
    while (a < bnd) { int mid = (a + bnd) >> 1; if (batch[mid] < g) a = mid + 1; else bnd = mid; }
    int start = a;
    bnd = NN;
    while (a < bnd) { int mid = (a + bnd) >> 1; if (batch[mid] <= g) a = mid + 1; else bnd = mid; }
    int end = a;
    float acc = 0.f;
    for (int n = start + w; n < end; n += 8) acc += h[(size_t)n * HC + c];
    red[w][c] = acc;
    __syncthreads();
    if (w == 0) {
        float s = red[0][c] + red[1][c] + red[2][c] + red[3][c]
                + red[4][c] + red[5][c] + red[6][c] + red[7][c];
        int count = end - start;
        out[g * HC + c] = s / (float)max(count, 1);
    }
}

// ---------------- launch ----------------

extern "C" void kernel_launch(void* const* d_in, const int* in_sizes, int n_in,
                              void* d_out, int out_size, void* d_ws, size_t ws_size,
                              hipStream_t stream) {
    const float* x     = (const float*)d_in[0];
    const int*   ei    = (const int*)d_in[1];
    const int*   batch = (const int*)d_in[2];
    const float* W_in  = (const float*)d_in[3];
    const float* b_in  = (const float*)d_in[4];
    const float* g_in  = (const float*)d_in[5];
    const float* be_in = (const float*)d_in[6];
    const float* W_tm  = (const float*)d_in[7];
    const float* b_tm  = (const float*)d_in[8];
    const float* tm_g  = (const float*)d_in[9];
    const float* tm_b  = (const float*)d_in[10];
    float* out = (float*)d_out;

    char* ws = (char*)d_ws;
    int*      cnt = (int*)(ws + 0);              // NN ints
    int*      fil = (int*)(ws + 200000);         // NN ints
    int*      rp  = (int*)(ws + 400000);         // NN+1 ints
    int*      col = (int*)(ws + 600004);         // NE ints   (ends at 3,000,004)
    float*    h   = (float*)(ws + 3000064);      // NN*HC fp32 (25.6 MB)
    ushort_t* h2  = (ushort_t*)(ws + 28600064);  // NN*HC bf16 (12.8 MB)
    float*    agg = (float*)(ws + 41400064);     // NN*HC fp32 (25.6 MB)
    float*    tm  = (float*)(ws + 67000064);     // NN*CHN fp32 (6.4 MB)
    int*      bsum = (int*)(ws + 73400064);      // SC_BLOCKS ints
    int*      boff = (int*)(ws + 73400320);      // SC_BLOCKS+1 ints

    hipMemsetAsync(cnt, 0, 400000, stream);       // cnt + fil (contiguous)
    hipMemsetAsync(tm, 0, 6400000, stream);       // last_tm_signal = 0

    k_hist<<<(NE + 255) / 256, 256, 0, stream>>>(ei, cnt);
    k_scanA<<<SC_BLOCKS, 256, 0, stream>>>(cnt, bsum);
    k_scanB<<<1, 64, 0, stream>>>(bsum, boff);
    k_scanC<<<SC_BLOCKS, 256, 0, stream>>>(cnt, boff, rp);
    k_fill<<<(NE + 255) / 256, 256, 0, stream>>>(ei, rp, fil, col);

    k_mlp<<<392, 256, 0, stream>>>(x, W_in, b_in, g_in, be_in, h, h2);

    for (int j = 0; j < 3; ++j) {
        k_agg<<<NN / 4, 256, 0, stream>>>(h2, rp, col, agg);
        k_update<<<1024, 256, 0, stream>>>(h, h2, agg, cnt, W_tm, b_tm, tm_g, tm_b, tm, j);
    }

    k_pool<<<NG, 1024, 0, stream>>>(h, batch, out);
}

// Round 7
// 484.781 us; speedup vs baseline: 1.1584x; 1.0794x over previous
//
#include <hip/hip_runtime.h>

#define NN 50000      // nodes
#define NE 600000     // edges
#define HC 128        // hidden channels
#define CHN 32        // chunk size
#define NG 64         // graphs
#define LN_EPS 1e-5f

typedef unsigned short ushort_t;
typedef unsigned int uint_t;

__device__ __forceinline__ ushort_t f2bf(float f) {   // RNE round to bf16
    uint_t u = __builtin_bit_cast(uint_t, f);
    u = (u + 0x7FFFu + ((u >> 16) & 1u)) >> 16;
    return (ushort_t)u;
}
__device__ __forceinline__ float bf2f(ushort_t s) {
    uint_t u = (uint_t)s << 16;
    return __builtin_bit_cast(float, u);
}

// ---------------- CSR build ----------------

__global__ void __launch_bounds__(256) k_hist(const int* __restrict__ ei, int* __restrict__ cnt) {
    int e = blockIdx.x * 256 + threadIdx.x;
    if (e >= NE) return;
    int s = ei[e], d = ei[NE + e];
    if (s != d) atomicAdd(&cnt[d], 1);
}

// ---- 3-phase device-wide exclusive scan of cnt[NN] -> row_ptr[NN+1] ----
#define SC_BLOCKS 49   // ceil(50000/1024)

__global__ void __launch_bounds__(256) k_scanA(const int* __restrict__ cnt, int* __restrict__ blocksum) {
    int b = blockIdx.x, t = threadIdx.x;
    int idx = b * 1024 + t * 4;
    int4 v = make_int4(0, 0, 0, 0);
    if (idx + 3 < NN) v = *(const int4*)&cnt[idx];
    else {
        if (idx + 0 < NN) v.x = cnt[idx + 0];
        if (idx + 1 < NN) v.y = cnt[idx + 1];
        if (idx + 2 < NN) v.z = cnt[idx + 2];
        if (idx + 3 < NN) v.w = cnt[idx + 3];
    }
    int s = v.x + v.y + v.z + v.w;
    for (int m = 1; m < 64; m <<= 1) s += __shfl_xor(s, m, 64);
    __shared__ int ws[4];
    if ((t & 63) == 0) ws[t >> 6] = s;
    __syncthreads();
    if (t == 0) blocksum[b] = ws[0] + ws[1] + ws[2] + ws[3];
}

__global__ void __launch_bounds__(64) k_scanB(const int* __restrict__ blocksum, int* __restrict__ blockoff) {
    int t = threadIdx.x;
    int v = (t < SC_BLOCKS) ? blocksum[t] : 0;
    int inc = v;
    for (int d = 1; d < 64; d <<= 1) { int u = __shfl_up(inc, d, 64); if (t >= d) inc += u; }
    if (t < SC_BLOCKS) blockoff[t + 1] = inc;
    if (t == 0) blockoff[0] = 0;
}

__global__ void __launch_bounds__(256) k_scanC(const int* __restrict__ cnt, const int* __restrict__ blockoff,
                                               int* __restrict__ row_ptr) {
    int b = blockIdx.x, t = threadIdx.x;
    int idx = b * 1024 + t * 4;
    int4 v = make_int4(0, 0, 0, 0);
    if (idx + 3 < NN) v = *(const int4*)&cnt[idx];
    else {
        if (idx + 0 < NN) v.x = cnt[idx + 0];
        if (idx + 1 < NN) v.y = cnt[idx + 1];
        if (idx + 2 < NN) v.z = cnt[idx + 2];
        if (idx + 3 < NN) v.w = cnt[idx + 3];
    }
    int s = v.x + v.y + v.z + v.w;
    int lane = t & 63, w = t >> 6;
    int inc = s;
    for (int d = 1; d < 64; d <<= 1) { int u = __shfl_up(inc, d, 64); if (lane >= d) inc += u; }
    __shared__ int wsum[4];
    if (lane == 63) wsum[w] = inc;
    __syncthreads();
    int off = blockoff[b];
    for (int i = 0; i < w; ++i) off += wsum[i];
    int excl = off + inc - s;
    if (idx + 0 < NN) row_ptr[idx + 0] = excl;
    if (idx + 1 < NN) row_ptr[idx + 1] = excl + v.x;
    if (idx + 2 < NN) row_ptr[idx + 2] = excl + v.x + v.y;
    if (idx + 3 < NN) row_ptr[idx + 3] = excl + v.x + v.y + v.z;
    if (b == 0 && t == 0) row_ptr[NN] = blockoff[SC_BLOCKS];
}

__global__ void __launch_bounds__(256) k_fill(const int* __restrict__ ei, const int* __restrict__ row_ptr,
                                              int* __restrict__ fill, int* __restrict__ col) {
    int e = blockIdx.x * 256 + threadIdx.x;
    if (e >= NE) return;
    int s = ei[e], d = ei[NE + e];
    if (s != d) {
        int pos = atomicAdd(&fill[d], 1);
        col[row_ptr[d] + pos] = s;
    }
}

// ---------------- input MLP: h = LN(relu(x @ W_in + b_in)) ----------------

#define MLP_NB 8
#define MLP_GROUPS (NN / MLP_NB)   // 6250, exact

__global__ void __launch_bounds__(256) k_mlp(const float* __restrict__ x, const float* __restrict__ W,
                                             const float* __restrict__ b, const float* __restrict__ g,
                                             const float* __restrict__ be, float* __restrict__ h,
                                             ushort_t* __restrict__ h2) {
    __shared__ float Ws[HC][HC];            // 64 KB
    __shared__ float xs[4][MLP_NB][HC];     // 16 KB
    int tid = threadIdx.x;
    for (int i = tid * 4; i < HC * HC; i += 256 * 4) {
        *(float4*)&((float*)Ws)[i] = *(const float4*)&W[i];
    }
    __syncthreads();
    int wave = tid >> 6, lane = tid & 63;
    float bx = b[2 * lane],  by = b[2 * lane + 1];
    float gx = g[2 * lane],  gy = g[2 * lane + 1];
    float bex = be[2 * lane], bey = be[2 * lane + 1];
    for (int grp = blockIdx.x * 4 + wave; grp < MLP_GROUPS; grp += gridDim.x * 4) {
        int base = grp * MLP_NB;
        #pragma unroll
        for (int nb = 0; nb < MLP_NB; ++nb) {
            float2 xv = *(const float2*)&x[(size_t)(base + nb) * HC + 2 * lane];
            *(float2*)&xs[wave][nb][2 * lane] = xv;
        }
        float ax[MLP_NB], ay[MLP_NB];
        #pragma unroll
        for (int nb = 0; nb < MLP_NB; ++nb) { ax[nb] = bx; ay[nb] = by; }
        for (int c = 0; c < HC; c += 4) {
            float2 wv0 = *(const float2*)&Ws[c + 0][2 * lane];
            float2 wv1 = *(const float2*)&Ws[c + 1][2 * lane];
            float2 wv2 = *(const float2*)&Ws[c + 2][2 * lane];
            float2 wv3 = *(const float2*)&Ws[c + 3][2 * lane];
            #pragma unroll
            for (int nb = 0; nb < MLP_NB; ++nb) {
                float4 xv = *(const float4*)&xs[wave][nb][c];
                ax[nb] = fmaf(xv.x, wv0.x, ax[nb]); ay[nb] = fmaf(xv.x, wv0.y, ay[nb]);
                ax[nb] = fmaf(xv.y, wv1.x, ax[nb]); ay[nb] = fmaf(xv.y, wv1.y, ay[nb]);
                ax[nb] = fmaf(xv.z, wv2.x, ax[nb]); ay[nb] = fmaf(xv.z, wv2.y, ay[nb]);
                ax[nb] = fmaf(xv.w, wv3.x, ax[nb]); ay[nb] = fmaf(xv.w, wv3.y, ay[nb]);
            }
        }
        #pragma unroll
        for (int nb = 0; nb < MLP_NB; ++nb) {
            float a0 = fmaxf(ax[nb], 0.f), a1 = fmaxf(ay[nb], 0.f);
            float sm = a0 + a1;
            for (int m = 1; m < 64; m <<= 1) sm += __shfl_xor(sm, m, 64);
            float mu = sm * (1.f / 128.f);
            float d0 = a0 - mu, d1 = a1 - mu;
            float vv = d0 * d0 + d1 * d1;
            for (int m = 1; m < 64; m <<= 1) vv += __shfl_xor(vv, m, 64);
            float inv = rsqrtf(vv * (1.f / 128.f) + LN_EPS);
            float2 o;
            o.x = d0 * inv * gx + bex;
            o.y = d1 * inv * gy + bey;
            *(float2*)&h[(size_t)(base + nb) * HC + 2 * lane] = o;
            ushort2 o2; o2.x = f2bf(o.x); o2.y = f2bf(o.y);
            *(ushort2*)&h2[(size_t)(base + nb) * HC + 2 * lane] = o2;
        }
    }
}

// ---------------- per-node CSR aggregation over bf16 mirror ----------------

__global__ void __launch_bounds__(256) k_agg(const ushort_t* __restrict__ h2, const int* __restrict__ row_ptr,
                                             const int* __restrict__ col, float* __restrict__ agg) {
    int wave = threadIdx.x >> 6, lane = threadIdx.x & 63;
    int node = blockIdx.x * 4 + wave;
    int r0 = row_ptr[node], r1 = row_ptr[node + 1];
    float ax = 0.f, ay = 0.f;
    for (int j = r0; j < r1; ++j) {
        int s = col[j];
        ushort2 hv = *(const ushort2*)&h2[(size_t)s * HC + 2 * lane];
        ax += bf2f(hv.x); ay += bf2f(hv.y);
    }
    float2 o; o.x = ax; o.y = ay;
    *(float2*)&agg[(size_t)node * HC + 2 * lane] = o;
}

// ---------------- fused node update (gating matmul + softmax + cumsum + mix + LN) ----------------
// 2 nodes per wave iteration. W transposed in LDS with 16B XOR swizzle so each
// lane streams its k-column via conflict-free ds_read_b128. gamma/beta/b_tm in regs.

__global__ void __launch_bounds__(256) k_update(float* __restrict__ h, ushort_t* __restrict__ h2,
        const float* __restrict__ agg,
        const int* __restrict__ cnt, const float* __restrict__ Wtm, const float* __restrict__ btm,
        const float* __restrict__ gall, const float* __restrict__ ball, float* __restrict__ tm, int layer) {
    __shared__ float Wt[CHN][256];         // 32 KB: Wt[k][j'] chunks, j' = j ^ (k&7)
    __shared__ float hm[4][2][2][HC];      // 8 KB: [wave][node][h|m][c]
    int tid = threadIdx.x;
    // stage transposed+swizzled W: chunk m -> k = m&31, j = m>>5 (0..63)
    for (int m = tid; m < 2048; m += 256) {
        int k = m & 31, j = m >> 5;
        float4 v;
        v.x = Wtm[(4 * j + 0) * CHN + k];
        v.y = Wtm[(4 * j + 1) * CHN + k];
        v.z = Wtm[(4 * j + 2) * CHN + k];
        v.w = Wtm[(4 * j + 3) * CHN + k];
        *(float4*)&Wt[k][(j ^ (k & 7)) << 2] = v;
    }
    __syncthreads();
    int wave = tid >> 6, lane = tid & 63;
    int k = lane & 31, half = lane >> 5;
    float bk  = btm[k];
    float gx  = gall[layer * HC + 2 * lane], gy  = gall[layer * HC + 2 * lane + 1];
    float bex = ball[layer * HC + 2 * lane], bey = ball[layer * HC + 2 * lane + 1];
    for (int pr = blockIdx.x * 4 + wave; pr < NN / 2; pr += gridDim.x * 4) {
        int n0 = pr * 2;
        float2 hv[2], av[2], mv[2];
        float tmo[2];
        #pragma unroll
        for (int nb = 0; nb < 2; ++nb) {
            hv[nb]  = *(const float2*)&h[(size_t)(n0 + nb) * HC + 2 * lane];
            av[nb]  = *(const float2*)&agg[(size_t)(n0 + nb) * HC + 2 * lane];
            tmo[nb] = tm[(size_t)(n0 + nb) * CHN + k];
        }
        float id0 = 1.f / (float)(cnt[n0] + 1);
        float id1 = 1.f / (float)(cnt[n0 + 1] + 1);
        mv[0].x = (av[0].x + hv[0].x) * id0; mv[0].y = (av[0].y + hv[0].y) * id0;
        mv[1].x = (av[1].x + hv[1].x) * id1; mv[1].y = (av[1].y + hv[1].y) * id1;
        #pragma unroll
        for (int nb = 0; nb < 2; ++nb) {
            *(float2*)&hm[wave][nb][0][2 * lane] = hv[nb];
            *(float2*)&hm[wave][nb][1][2 * lane] = mv[nb];
        }
        // z-loop: lane computes z_k for its half's 128-length dot (order c-sequential)
        float z0 = 0.f, z1 = 0.f;
        #pragma unroll 8
        for (int cq = 0; cq < 32; ++cq) {
            float4 wv = *(const float4*)&Wt[k][((half * 32 + cq) ^ (k & 7)) << 2];
            float4 s0 = *(const float4*)&hm[wave][0][half][cq * 4];
            float4 s1 = *(const float4*)&hm[wave][1][half][cq * 4];
            z0 = fmaf(s0.x, wv.x, z0); z0 = fmaf(s0.y, wv.y, z0);
            z0 = fmaf(s0.z, wv.z, z0); z0 = fmaf(s0.w, wv.w, z0);
            z1 = fmaf(s1.x, wv.x, z1); z1 = fmaf(s1.y, wv.y, z1);
            z1 = fmaf(s1.z, wv.z, z1); z1 = fmaf(s1.w, wv.w, z1);
        }
        #pragma unroll
        for (int nb = 0; nb < 2; ++nb) {
            float z = nb ? z1 : z0;
            z += __shfl_xor(z, 32, 64);      // combine the two K-halves
            z += bk;
            // softmax over 32 gates (width-32: both halves identical)
            float mx = z;
            for (int m = 1; m < 32; m <<= 1) mx = fmaxf(mx, __shfl_xor(mx, m, 32));
            float e = expf(z - mx);
            float se = e;
            for (int m = 1; m < 32; m <<= 1) se += __shfl_xor(se, m, 32);
            float p = e / se;
            // inclusive cumsum over gate index k
            float cum = p;
            for (int d = 1; d < 32; d <<= 1) {
                float t2 = __shfl_up(cum, d, 32);
                if (k >= d) cum += t2;
            }
            float raw = tmo[nb] + (1.f - tmo[nb]) * cum;
            if (half == 0) tm[(size_t)(n0 + nb) * CHN + k] = raw;
            float sig = __shfl(raw, lane >> 1, 64);
            float v0 = hv[nb].x * sig + mv[nb].x * (1.f - sig);
            float v1 = hv[nb].y * sig + mv[nb].y * (1.f - sig);
            float sm = v0 + v1;
            for (int m = 1; m < 64; m <<= 1) sm += __shfl_xor(sm, m, 64);
            float mu = sm * (1.f / 128.f);
            float d0 = v0 - mu, d1 = v1 - mu;
            float vv = d0 * d0 + d1 * d1;
            for (int m = 1; m < 64; m <<= 1) vv += __shfl_xor(vv, m, 64);
            float inv = rsqrtf(vv * (1.f / 128.f) + LN_EPS);
            float2 o;
            o.x = d0 * inv * gx + bex;
            o.y = d1 * inv * gy + bey;
            *(float2*)&h[(size_t)(n0 + nb) * HC + 2 * lane] = o;
            ushort2 o2; o2.x = f2bf(o.x); o2.y = f2bf(o.y);
            *(ushort2*)&h2[(size_t)(n0 + nb) * HC + 2 * lane] = o2;
        }
    }
}

// ---------------- global mean pool (batch is sorted) ----------------

__global__ void __launch_bounds__(1024) k_pool(const float* __restrict__ h, const int* __restrict__ batch,
                                               float* __restrict__ out) {
    __shared__ float red[8][HC];
    int g = blockIdx.x;
    int tid = threadIdx.x;
    int c = tid & (HC - 1);
    int w = tid >> 7;          // 0..7 node-slice
    int a = 0, bnd = NN;
    while (a < bnd) { int mid = (a + bnd) >> 1; if (batch[mid] < g) a = mid + 1; else bnd = mid; }
    int start = a;
    bnd = NN;
    while (a < bnd) { int mid = (a + bnd) >> 1; if (batch[mid] <= g) a = mid + 1; else bnd = mid; }
    int end = a;
    float acc = 0.f;
    for (int n = start + w; n < end; n += 8) acc += h[(size_t)n * HC + c];
    red[w][c] = acc;
    __syncthreads();
    if (w == 0) {
        float s = red[0][c] + red[1][c] + red[2][c] + red[3][c]
                + red[4][c] + red[5][c] + red[6][c] + red[7][c];
        int count = end - start;
        out[g * HC + c] = s / (float)max(count, 1);
    }
}

// ---------------- launch ----------------

extern "C" void kernel_launch(void* const* d_in, const int* in_sizes, int n_in,
                              void* d_out, int out_size, void* d_ws, size_t ws_size,
                              hipStream_t stream) {
    const float* x     = (const float*)d_in[0];
    const int*   ei    = (const int*)d_in[1];
    const int*   batch = (const int*)d_in[2];
    const float* W_in  = (const float*)d_in[3];
    const float* b_in  = (const float*)d_in[4];
    const float* g_in  = (const float*)d_in[5];
    const float* be_in = (const float*)d_in[6];
    const float* W_tm  = (const float*)d_in[7];
    const float* b_tm  = (const float*)d_in[8];
    const float* tm_g  = (const float*)d_in[9];
    const float* tm_b  = (const float*)d_in[10];
    float* out = (float*)d_out;

    char* ws = (char*)d_ws;
    int*      cnt = (int*)(ws + 0);              // NN ints
    int*      fil = (int*)(ws + 200000);         // NN ints
    int*      rp  = (int*)(ws + 400000);         // NN+1 ints
    int*      col = (int*)(ws + 600004);         // NE ints   (ends at 3,000,004)
    float*    h   = (float*)(ws + 3000064);      // NN*HC fp32 (25.6 MB)
    ushort_t* h2  = (ushort_t*)(ws + 28600064);  // NN*HC bf16 (12.8 MB)
    float*    agg = (float*)(ws + 41400064);     // NN*HC fp32 (25.6 MB)
    float*    tm  = (float*)(ws + 67000064);     // NN*CHN fp32 (6.4 MB)
    int*      bsum = (int*)(ws + 73400064);      // SC_BLOCKS ints
    int*      boff = (int*)(ws + 73400320);      // SC_BLOCKS+1 ints

    hipMemsetAsync(cnt, 0, 400000, stream);       // cnt + fil (contiguous)
    hipMemsetAsync(tm, 0, 6400000, stream);       // last_tm_signal = 0

    k_hist<<<(NE + 255) / 256, 256, 0, stream>>>(ei, cnt);
    k_scanA<<<SC_BLOCKS, 256, 0, stream>>>(cnt, bsum);
    k_scanB<<<1, 64, 0, stream>>>(bsum, boff);
    k_scanC<<<SC_BLOCKS, 256, 0, stream>>>(cnt, boff, rp);
    k_fill<<<(NE + 255) / 256, 256, 0, stream>>>(ei, rp, fil, col);

    k_mlp<<<392, 256, 0, stream>>>(x, W_in, b_in, g_in, be_in, h, h2);

    for (int j = 0; j < 3; ++j) {
        k_agg<<<NN / 4, 256, 0, stream>>>(h2, rp, col, agg);
        k_update<<<1024, 256, 0, stream>>>(h, h2, agg, cnt, W_tm, b_tm, tm_g, tm_b, tm, j);
    }

    k_pool<<<NG, 1024, 0, stream>>>(h, batch, out);
}

// Round 8
// 374.489 us; speedup vs baseline: 1.4995x; 1.2945x over previous
//
#include <hip/hip_runtime.h>

#define NN 50000      // nodes
#define NE 600000     // edges
#define HC 128        // hidden channels
#define CHN 32        // chunk size
#define NG 64         // graphs
#define LN_EPS 1e-5f

typedef unsigned short ushort_t;
typedef unsigned int uint_t;

__device__ __forceinline__ ushort_t f2bf(float f) {   // RNE round to bf16
    uint_t u = __builtin_bit_cast(uint_t, f);
    u = (u + 0x7FFFu + ((u >> 16) & 1u)) >> 16;
    return (ushort_t)u;
}
__device__ __forceinline__ float bf2f(ushort_t s) {
    uint_t u = (uint_t)s << 16;
    return __builtin_bit_cast(float, u);
}

// ---------------- CSR build ----------------

__global__ void __launch_bounds__(256) k_hist(const int* __restrict__ ei, int* __restrict__ cnt) {
    int e = blockIdx.x * 256 + threadIdx.x;
    if (e >= NE) return;
    int s = ei[e], d = ei[NE + e];
    if (s != d) atomicAdd(&cnt[d], 1);
}

// ---- 3-phase device-wide exclusive scan of cnt[NN] -> row_ptr[NN+1] ----
#define SC_BLOCKS 49   // ceil(50000/1024)

__global__ void __launch_bounds__(256) k_scanA(const int* __restrict__ cnt, int* __restrict__ blocksum) {
    int b = blockIdx.x, t = threadIdx.x;
    int idx = b * 1024 + t * 4;
    int4 v = make_int4(0, 0, 0, 0);
    if (idx + 3 < NN) v = *(const int4*)&cnt[idx];
    else {
        if (idx + 0 < NN) v.x = cnt[idx + 0];
        if (idx + 1 < NN) v.y = cnt[idx + 1];
        if (idx + 2 < NN) v.z = cnt[idx + 2];
        if (idx + 3 < NN) v.w = cnt[idx + 3];
    }
    int s = v.x + v.y + v.z + v.w;
    for (int m = 1; m < 64; m <<= 1) s += __shfl_xor(s, m, 64);
    __shared__ int ws[4];
    if ((t & 63) == 0) ws[t >> 6] = s;
    __syncthreads();
    if (t == 0) blocksum[b] = ws[0] + ws[1] + ws[2] + ws[3];
}

__global__ void __launch_bounds__(64) k_scanB(const int* __restrict__ blocksum, int* __restrict__ blockoff) {
    int t = threadIdx.x;
    int v = (t < SC_BLOCKS) ? blocksum[t] : 0;
    int inc = v;
    for (int d = 1; d < 64; d <<= 1) { int u = __shfl_up(inc, d, 64); if (t >= d) inc += u; }
    if (t < SC_BLOCKS) blockoff[t + 1] = inc;
    if (t == 0) blockoff[0] = 0;
}

__global__ void __launch_bounds__(256) k_scanC(const int* __restrict__ cnt, const int* __restrict__ blockoff,
                                               int* __restrict__ row_ptr) {
    int b = blockIdx.x, t = threadIdx.x;
    int idx = b * 1024 + t * 4;
    int4 v = make_int4(0, 0, 0, 0);
    if (idx + 3 < NN) v = *(const int4*)&cnt[idx];
    else {
        if (idx + 0 < NN) v.x = cnt[idx + 0];
        if (idx + 1 < NN) v.y = cnt[idx + 1];
        if (idx + 2 < NN) v.z = cnt[idx + 2];
        if (idx + 3 < NN) v.w = cnt[idx + 3];
    }
    int s = v.x + v.y + v.z + v.w;
    int lane = t & 63, w = t >> 6;
    int inc = s;
    for (int d = 1; d < 64; d <<= 1) { int u = __shfl_up(inc, d, 64); if (lane >= d) inc += u; }
    __shared__ int wsum[4];
    if (lane == 63) wsum[w] = inc;
    __syncthreads();
    int off = blockoff[b];
    for (int i = 0; i < w; ++i) off += wsum[i];
    int excl = off + inc - s;
    if (idx + 0 < NN) row_ptr[idx + 0] = excl;
    if (idx + 1 < NN) row_ptr[idx + 1] = excl + v.x;
    if (idx + 2 < NN) row_ptr[idx + 2] = excl + v.x + v.y;
    if (idx + 3 < NN) row_ptr[idx + 3] = excl + v.x + v.y + v.z;
    if (b == 0 && t == 0) row_ptr[NN] = blockoff[SC_BLOCKS];
}

__global__ void __launch_bounds__(256) k_fill(const int* __restrict__ ei, const int* __restrict__ row_ptr,
                                              int* __restrict__ fill, int* __restrict__ col) {
    int e = blockIdx.x * 256 + threadIdx.x;
    if (e >= NE) return;
    int s = ei[e], d = ei[NE + e];
    if (s != d) {
        int pos = atomicAdd(&fill[d], 1);
        col[row_ptr[d] + pos] = s;
    }
}

// ---------------- input MLP: h = LN(relu(x @ W_in + b_in)) ----------------
// x rows staged per-wave in LDS; W streamed from global (L1/L2-cached, amortized
// over NB=8 nodes). LDS = 16 KB -> ~5 blocks/CU (VGPR-limited), vs 80 KB before.

#define MLP_NB 8
#define MLP_GROUPS (NN / MLP_NB)   // 6250, exact

__global__ void __launch_bounds__(256) k_mlp(const float* __restrict__ x, const float* __restrict__ W,
                                             const float* __restrict__ b, const float* __restrict__ g,
                                             const float* __restrict__ be, float* __restrict__ h,
                                             ushort_t* __restrict__ h2) {
    __shared__ float xs[4][MLP_NB][HC];     // 16 KB
    int tid = threadIdx.x;
    int wave = tid >> 6, lane = tid & 63;
    float bx = b[2 * lane],  by = b[2 * lane + 1];
    float gx = g[2 * lane],  gy = g[2 * lane + 1];
    float bex = be[2 * lane], bey = be[2 * lane + 1];
    for (int grp = blockIdx.x * 4 + wave; grp < MLP_GROUPS; grp += gridDim.x * 4) {
        int base = grp * MLP_NB;
        #pragma unroll
        for (int nb = 0; nb < MLP_NB; ++nb) {
            float2 xv = *(const float2*)&x[(size_t)(base + nb) * HC + 2 * lane];
            *(float2*)&xs[wave][nb][2 * lane] = xv;
        }
        float ax[MLP_NB], ay[MLP_NB];
        #pragma unroll
        for (int nb = 0; nb < MLP_NB; ++nb) { ax[nb] = bx; ay[nb] = by; }
        // wave-local LDS: compiler inserts lgkmcnt waits; no block barrier needed
        for (int c = 0; c < HC; c += 4) {
            float2 wv0 = *(const float2*)&W[(c + 0) * HC + 2 * lane];
            float2 wv1 = *(const float2*)&W[(c + 1) * HC + 2 * lane];
            float2 wv2 = *(const float2*)&W[(c + 2) * HC + 2 * lane];
            float2 wv3 = *(const float2*)&W[(c + 3) * HC + 2 * lane];
            #pragma unroll
            for (int nb = 0; nb < MLP_NB; ++nb) {
                float4 xv = *(const float4*)&xs[wave][nb][c];
                ax[nb] = fmaf(xv.x, wv0.x, ax[nb]); ay[nb] = fmaf(xv.x, wv0.y, ay[nb]);
                ax[nb] = fmaf(xv.y, wv1.x, ax[nb]); ay[nb] = fmaf(xv.y, wv1.y, ay[nb]);
                ax[nb] = fmaf(xv.z, wv2.x, ax[nb]); ay[nb] = fmaf(xv.z, wv2.y, ay[nb]);
                ax[nb] = fmaf(xv.w, wv3.x, ax[nb]); ay[nb] = fmaf(xv.w, wv3.y, ay[nb]);
            }
        }
        #pragma unroll
        for (int nb = 0; nb < MLP_NB; ++nb) {
            float a0 = fmaxf(ax[nb], 0.f), a1 = fmaxf(ay[nb], 0.f);
            float sm = a0 + a1;
            for (int m = 1; m < 64; m <<= 1) sm += __shfl_xor(sm, m, 64);
            float mu = sm * (1.f / 128.f);
            float d0 = a0 - mu, d1 = a1 - mu;
            float vv = d0 * d0 + d1 * d1;
            for (int m = 1; m < 64; m <<= 1) vv += __shfl_xor(vv, m, 64);
            float inv = rsqrtf(vv * (1.f / 128.f) + LN_EPS);
            float2 o;
            o.x = d0 * inv * gx + bex;
            o.y = d1 * inv * gy + bey;
            *(float2*)&h[(size_t)(base + nb) * HC + 2 * lane] = o;
            ushort2 o2; o2.x = f2bf(o.x); o2.y = f2bf(o.y);
            *(ushort2*)&h2[(size_t)(base + nb) * HC + 2 * lane] = o2;
        }
    }
}

// ---------------- per-node CSR aggregation over bf16 mirror ----------------
// Lane-parallel index fetch (64 cols per coalesced load, shfl broadcast) +
// 4x unrolled row loads -> 4 outstanding 256B gathers per wave.

__global__ void __launch_bounds__(256) k_agg(const ushort_t* __restrict__ h2, const int* __restrict__ row_ptr,
                                             const int* __restrict__ col, float* __restrict__ agg) {
    int wave = threadIdx.x >> 6, lane = threadIdx.x & 63;
    int node = blockIdx.x * 4 + wave;
    int r0 = row_ptr[node], r1 = row_ptr[node + 1];
    int deg = r1 - r0;
    float ax = 0.f, ay = 0.f;
    for (int base = 0; base < deg; base += 64) {
        int nIdx = min(64, deg - base);
        int myc = (base + lane < deg) ? col[r0 + base + lane] : 0;
        int j = 0;
        for (; j + 4 <= nIdx; j += 4) {
            int s0 = __shfl(myc, j,     64);
            int s1 = __shfl(myc, j + 1, 64);
            int s2 = __shfl(myc, j + 2, 64);
            int s3 = __shfl(myc, j + 3, 64);
            ushort2 v0 = *(const ushort2*)&h2[(size_t)s0 * HC + 2 * lane];
            ushort2 v1 = *(const ushort2*)&h2[(size_t)s1 * HC + 2 * lane];
            ushort2 v2 = *(const ushort2*)&h2[(size_t)s2 * HC + 2 * lane];
            ushort2 v3 = *(const ushort2*)&h2[(size_t)s3 * HC + 2 * lane];
            ax += bf2f(v0.x); ay += bf2f(v0.y);
            ax += bf2f(v1.x); ay += bf2f(v1.y);
            ax += bf2f(v2.x); ay += bf2f(v2.y);
            ax += bf2f(v3.x); ay += bf2f(v3.y);
        }
        for (; j < nIdx; ++j) {
            int s = __shfl(myc, j, 64);
            ushort2 hv = *(const ushort2*)&h2[(size_t)s * HC + 2 * lane];
            ax += bf2f(hv.x); ay += bf2f(hv.y);
        }
    }
    float2 o; o.x = ax; o.y = ay;
    *(float2*)&agg[(size_t)node * HC + 2 * lane] = o;
}

// ---------------- fused node update (gating matmul + softmax + cumsum + mix + LN) ----------------
// 2 nodes per wave iteration. W transposed in LDS with 16B XOR swizzle so each
// lane streams its k-column via conflict-free ds_read_b128. gamma/beta/b_tm in regs.

__global__ void __launch_bounds__(256) k_update(float* __restrict__ h, ushort_t* __restrict__ h2,
        const float* __restrict__ agg,
        const int* __restrict__ cnt, const float* __restrict__ Wtm, const float* __restrict__ btm,
        const float* __restrict__ gall, const float* __restrict__ ball, float* __restrict__ tm, int layer) {
    __shared__ float Wt[CHN][256];         // 32 KB: Wt[k][j'] chunks, j' = j ^ (k&7)
    __shared__ float hm[4][2][2][HC];      // 8 KB: [wave][node][h|m][c]
    int tid = threadIdx.x;
    // stage transposed+swizzled W: chunk m -> k = m&31, j = m>>5 (0..63)
    for (int m = tid; m < 2048; m += 256) {
        int k = m & 31, j = m >> 5;
        float4 v;
        v.x = Wtm[(4 * j + 0) * CHN + k];
        v.y = Wtm[(4 * j + 1) * CHN + k];
        v.z = Wtm[(4 * j + 2) * CHN + k];
        v.w = Wtm[(4 * j + 3) * CHN + k];
        *(float4*)&Wt[k][(j ^ (k & 7)) << 2] = v;
    }
    __syncthreads();
    int wave = tid >> 6, lane = tid & 63;
    int k = lane & 31, half = lane >> 5;
    float bk  = btm[k];
    float gx  = gall[layer * HC + 2 * lane], gy  = gall[layer * HC + 2 * lane + 1];
    float bex = ball[layer * HC + 2 * lane], bey = ball[layer * HC + 2 * lane + 1];
    for (int pr = blockIdx.x * 4 + wave; pr < NN / 2; pr += gridDim.x * 4) {
        int n0 = pr * 2;
        float2 hv[2], av[2], mv[2];
        float tmo[2];
        #pragma unroll
        for (int nb = 0; nb < 2; ++nb) {
            hv[nb]  = *(const float2*)&h[(size_t)(n0 + nb) * HC + 2 * lane];
            av[nb]  = *(const float2*)&agg[(size_t)(n0 + nb) * HC + 2 * lane];
            tmo[nb] = tm[(size_t)(n0 + nb) * CHN + k];
        }
        float id0 = 1.f / (float)(cnt[n0] + 1);
        float id1 = 1.f / (float)(cnt[n0 + 1] + 1);
        mv[0].x = (av[0].x + hv[0].x) * id0; mv[0].y = (av[0].y + hv[0].y) * id0;
        mv[1].x = (av[1].x + hv[1].x) * id1; mv[1].y = (av[1].y + hv[1].y) * id1;
        #pragma unroll
        for (int nb = 0; nb < 2; ++nb) {
            *(float2*)&hm[wave][nb][0][2 * lane] = hv[nb];
            *(float2*)&hm[wave][nb][1][2 * lane] = mv[nb];
        }
        // z-loop: lane computes z_k for its half's 128-length dot (order c-sequential)
        float z0 = 0.f, z1 = 0.f;
        #pragma unroll 8
        for (int cq = 0; cq < 32; ++cq) {
            float4 wv = *(const float4*)&Wt[k][((half * 32 + cq) ^ (k & 7)) << 2];
            float4 s0 = *(const float4*)&hm[wave][0][half][cq * 4];
            float4 s1 = *(const float4*)&hm[wave][1][half][cq * 4];
            z0 = fmaf(s0.x, wv.x, z0); z0 = fmaf(s0.y, wv.y, z0);
            z0 = fmaf(s0.z, wv.z, z0); z0 = fmaf(s0.w, wv.w, z0);
            z1 = fmaf(s1.x, wv.x, z1); z1 = fmaf(s1.y, wv.y, z1);
            z1 = fmaf(s1.z, wv.z, z1); z1 = fmaf(s1.w, wv.w, z1);
        }
        #pragma unroll
        for (int nb = 0; nb < 2; ++nb) {
            float z = nb ? z1 : z0;
            z += __shfl_xor(z, 32, 64);      // combine the two K-halves
            z += bk;
            // softmax over 32 gates (width-32: both halves identical)
            float mx = z;
            for (int m = 1; m < 32; m <<= 1) mx = fmaxf(mx, __shfl_xor(mx, m, 32));
            float e = expf(z - mx);
            float se = e;
            for (int m = 1; m < 32; m <<= 1) se += __shfl_xor(se, m, 32);
            float p = e / se;
            // inclusive cumsum over gate index k
            float cum = p;
            for (int d = 1; d < 32; d <<= 1) {
                float t2 = __shfl_up(cum, d, 32);
                if (k >= d) cum += t2;
            }
            float raw = tmo[nb] + (1.f - tmo[nb]) * cum;
            if (half == 0) tm[(size_t)(n0 + nb) * CHN + k] = raw;
            float sig = __shfl(raw, lane >> 1, 64);
            float v0 = hv[nb].x * sig + mv[nb].x * (1.f - sig);
            float v1 = hv[nb].y * sig + mv[nb].y * (1.f - sig);
            float sm = v0 + v1;
            for (int m = 1; m < 64; m <<= 1) sm += __shfl_xor(sm, m, 64);
            float mu = sm * (1.f / 128.f);
            float d0 = v0 - mu, d1 = v1 - mu;
            float vv = d0 * d0 + d1 * d1;
            for (int m = 1; m < 64; m <<= 1) vv += __shfl_xor(vv, m, 64);
            float inv = rsqrtf(vv * (1.f / 128.f) + LN_EPS);
            float2 o;
            o.x = d0 * inv * gx + bex;
            o.y = d1 * inv * gy + bey;
            *(float2*)&h[(size_t)(n0 + nb) * HC + 2 * lane] = o;
            ushort2 o2; o2.x = f2bf(o.x); o2.y = f2bf(o.y);
            *(ushort2*)&h2[(size_t)(n0 + nb) * HC + 2 * lane] = o2;
        }
    }
}

// ---------------- global mean pool (batch is sorted) ----------------

__global__ void __launch_bounds__(1024) k_pool(const float* __restrict__ h, const int* __restrict__ batch,
                                               float* __restrict__ out) {
    __shared__ float red[8][HC];
    int g = blockIdx.x;
    int tid = threadIdx.x;
    int c = tid & (HC - 1);
    int w = tid >> 7;          // 0..7 node-slice
    int a = 0, bnd = NN;
    while (a < bnd) { int mid = (a + bnd) >> 1; if (batch[mid] < g) a = mid + 1; else bnd = mid; }
    int start = a;
    bnd = NN;
    while (a < bnd) { int mid = (a + bnd) >> 1; if (batch[mid] <= g) a = mid + 1; else bnd = mid; }
    int end = a;
    float acc = 0.f;
    for (int n = start + w; n < end; n += 8) acc += h[(size_t)n * HC + c];
    red[w][c] = acc;
    __syncthreads();
    if (w == 0) {
        float s = red[0][c] + red[1][c] + red[2][c] + red[3][c]
                + red[4][c] + red[5][c] + red[6][c] + red[7][c];
        int count = end - start;
        out[g * HC + c] = s / (float)max(count, 1);
    }
}

// ---------------- launch ----------------

extern "C" void kernel_launch(void* const* d_in, const int* in_sizes, int n_in,
                              void* d_out, int out_size, void* d_ws, size_t ws_size,
                              hipStream_t stream) {
    const float* x     = (const float*)d_in[0];
    const int*   ei    = (const int*)d_in[1];
    const int*   batch = (const int*)d_in[2];
    const float* W_in  = (const float*)d_in[3];
    const float* b_in  = (const float*)d_in[4];
    const float* g_in  = (const float*)d_in[5];
    const float* be_in = (const float*)d_in[6];
    const float* W_tm  = (const float*)d_in[7];
    const float* b_tm  = (const float*)d_in[8];
    const float* tm_g  = (const float*)d_in[9];
    const float* tm_b  = (const float*)d_in[10];
    float* out = (float*)d_out;

    char* ws = (char*)d_ws;
    int*      cnt = (int*)(ws + 0);              // NN ints
    int*      fil = (int*)(ws + 200000);         // NN ints
    int*      rp  = (int*)(ws + 400000);         // NN+1 ints
    int*      col = (int*)(ws + 600004);         // NE ints   (ends at 3,000,004)
    float*    h   = (float*)(ws + 3000064);      // NN*HC fp32 (25.6 MB)
    ushort_t* h2  = (ushort_t*)(ws + 28600064);  // NN*HC bf16 (12.8 MB)
    float*    agg = (float*)(ws + 41400064);     // NN*HC fp32 (25.6 MB)
    float*    tm  = (float*)(ws + 67000064);     // NN*CHN fp32 (6.4 MB)
    int*      bsum = (int*)(ws + 73400064);      // SC_BLOCKS ints
    int*      boff = (int*)(ws + 73400320);      // SC_BLOCKS+1 ints

    hipMemsetAsync(cnt, 0, 400000, stream);       // cnt + fil (contiguous)
    hipMemsetAsync(tm, 0, 6400000, stream);       // last_tm_signal = 0

    k_hist<<<(NE + 255) / 256, 256, 0, stream>>>(ei, cnt);
    k_scanA<<<SC_BLOCKS, 256, 0, stream>>>(cnt, bsum);
    k_scanB<<<1, 64, 0, stream>>>(bsum, boff);
    k_scanC<<<SC_BLOCKS, 256, 0, stream>>>(cnt, boff, rp);
    k_fill<<<(NE + 255) / 256, 256, 0, stream>>>(ei, rp, fil, col);

    k_mlp<<<1563, 256, 0, stream>>>(x, W_in, b_in, g_in, be_in, h, h2);

    for (int j = 0; j < 3; ++j) {
        k_agg<<<NN / 4, 256, 0, stream>>>(h2, rp, col, agg);
        k_update<<<1024, 256, 0, stream>>>(h, h2, agg, cnt, W_tm, b_tm, tm_g, tm_b, tm, j);
    }

    k_pool<<<NG, 1024, 0, stream>>>(h, batch, out);
}

// Round 9
// 371.708 us; speedup vs baseline: 1.5107x; 1.0075x over previous
//
#include <hip/hip_runtime.h>

#define NN 50000      // nodes
#define NE 600000     // edges
#define HC 128        // hidden channels
#define CHN 32        // chunk size
#define NG 64         // graphs
#define LN_EPS 1e-5f

typedef unsigned short ushort_t;
typedef unsigned int uint_t;

__device__ __forceinline__ ushort_t f2bf(float f) {   // RNE round to bf16
    uint_t u = __builtin_bit_cast(uint_t, f);
    u = (u + 0x7FFFu + ((u >> 16) & 1u)) >> 16;
    return (ushort_t)u;
}
__device__ __forceinline__ float bf2f(ushort_t s) {
    uint_t u = (uint_t)s << 16;
    return __builtin_bit_cast(float, u);
}
__device__ __forceinline__ float bchi(uint_t u) {     // high bf16 of packed u32 -> float
    return __builtin_bit_cast(float, u & 0xFFFF0000u);
}
__device__ __forceinline__ float bclo(uint_t u) {     // low bf16 -> float
    return __builtin_bit_cast(float, u << 16);
}

// ---------------- CSR build ----------------

__global__ void __launch_bounds__(256) k_hist(const int* __restrict__ ei, int* __restrict__ cnt) {
    int e = blockIdx.x * 256 + threadIdx.x;
    if (e >= NE) return;
    int s = ei[e], d = ei[NE + e];
    if (s != d) atomicAdd(&cnt[d], 1);
}

// ---- 3-phase device-wide exclusive scan of cnt[NN] -> row_ptr[NN+1] ----
#define SC_BLOCKS 49   // ceil(50000/1024)

__global__ void __launch_bounds__(256) k_scanA(const int* __restrict__ cnt, int* __restrict__ blocksum) {
    int b = blockIdx.x, t = threadIdx.x;
    int idx = b * 1024 + t * 4;
    int4 v = make_int4(0, 0, 0, 0);
    if (idx + 3 < NN) v = *(const int4*)&cnt[idx];
    else {
        if (idx + 0 < NN) v.x = cnt[idx + 0];
        if (idx + 1 < NN) v.y = cnt[idx + 1];
        if (idx + 2 < NN) v.z = cnt[idx + 2];
        if (idx + 3 < NN) v.w = cnt[idx + 3];
    }
    int s = v.x + v.y + v.z + v.w;
    for (int m = 1; m < 64; m <<= 1) s += __shfl_xor(s, m, 64);
    __shared__ int ws[4];
    if ((t & 63) == 0) ws[t >> 6] = s;
    __syncthreads();
    if (t == 0) blocksum[b] = ws[0] + ws[1] + ws[2] + ws[3];
}

__global__ void __launch_bounds__(64) k_scanB(const int* __restrict__ blocksum, int* __restrict__ blockoff) {
    int t = threadIdx.x;
    int v = (t < SC_BLOCKS) ? blocksum[t] : 0;
    int inc = v;
    for (int d = 1; d < 64; d <<= 1) { int u = __shfl_up(inc, d, 64); if (t >= d) inc += u; }
    if (t < SC_BLOCKS) blockoff[t + 1] = inc;
    if (t == 0) blockoff[0] = 0;
}

__global__ void __launch_bounds__(256) k_scanC(const int* __restrict__ cnt, const int* __restrict__ blockoff,
                                               int* __restrict__ row_ptr) {
    int b = blockIdx.x, t = threadIdx.x;
    int idx = b * 1024 + t * 4;
    int4 v = make_int4(0, 0, 0, 0);
    if (idx + 3 < NN) v = *(const int4*)&cnt[idx];
    else {
        if (idx + 0 < NN) v.x = cnt[idx + 0];
        if (idx + 1 < NN) v.y = cnt[idx + 1];
        if (idx + 2 < NN) v.z = cnt[idx + 2];
        if (idx + 3 < NN) v.w = cnt[idx + 3];
    }
    int s = v.x + v.y + v.z + v.w;
    int lane = t & 63, w = t >> 6;
    int inc = s;
    for (int d = 1; d < 64; d <<= 1) { int u = __shfl_up(inc, d, 64); if (lane >= d) inc += u; }
    __shared__ int wsum[4];
    if (lane == 63) wsum[w] = inc;
    __syncthreads();
    int off = blockoff[b];
    for (int i = 0; i < w; ++i) off += wsum[i];
    int excl = off + inc - s;
    if (idx + 0 < NN) row_ptr[idx + 0] = excl;
    if (idx + 1 < NN) row_ptr[idx + 1] = excl + v.x;
    if (idx + 2 < NN) row_ptr[idx + 2] = excl + v.x + v.y;
    if (idx + 3 < NN) row_ptr[idx + 3] = excl + v.x + v.y + v.z;
    if (b == 0 && t == 0) row_ptr[NN] = blockoff[SC_BLOCKS];
}

__global__ void __launch_bounds__(256) k_fill(const int* __restrict__ ei, const int* __restrict__ row_ptr,
                                              int* __restrict__ fill, int* __restrict__ col) {
    int e = blockIdx.x * 256 + threadIdx.x;
    if (e >= NE) return;
    int s = ei[e], d = ei[NE + e];
    if (s != d) {
        int pos = atomicAdd(&fill[d], 1);
        col[row_ptr[d] + pos] = s;
    }
}

// ---------------- input MLP: h = LN(relu(x @ W_in + b_in)) ----------------

#define MLP_NB 8
#define MLP_GROUPS (NN / MLP_NB)   // 6250, exact

__global__ void __launch_bounds__(256) k_mlp(const float* __restrict__ x, const float* __restrict__ W,
                                             const float* __restrict__ b, const float* __restrict__ g,
                                             const float* __restrict__ be, float* __restrict__ h,
                                             ushort_t* __restrict__ h2) {
    __shared__ float xs[4][MLP_NB][HC];     // 16 KB
    int tid = threadIdx.x;
    int wave = tid >> 6, lane = tid & 63;
    float bx = b[2 * lane],  by = b[2 * lane + 1];
    float gx = g[2 * lane],  gy = g[2 * lane + 1];
    float bex = be[2 * lane], bey = be[2 * lane + 1];
    for (int grp = blockIdx.x * 4 + wave; grp < MLP_GROUPS; grp += gridDim.x * 4) {
        int base = grp * MLP_NB;
        #pragma unroll
        for (int nb = 0; nb < MLP_NB; ++nb) {
            float2 xv = *(const float2*)&x[(size_t)(base + nb) * HC + 2 * lane];
            *(float2*)&xs[wave][nb][2 * lane] = xv;
        }
        float ax[MLP_NB], ay[MLP_NB];
        #pragma unroll
        for (int nb = 0; nb < MLP_NB; ++nb) { ax[nb] = bx; ay[nb] = by; }
        // wave-local LDS: compiler inserts lgkmcnt waits; no block barrier needed
        for (int c = 0; c < HC; c += 4) {
            float2 wv0 = *(const float2*)&W[(c + 0) * HC + 2 * lane];
            float2 wv1 = *(const float2*)&W[(c + 1) * HC + 2 * lane];
            float2 wv2 = *(const float2*)&W[(c + 2) * HC + 2 * lane];
            float2 wv3 = *(const float2*)&W[(c + 3) * HC + 2 * lane];
            #pragma unroll
            for (int nb = 0; nb < MLP_NB; ++nb) {
                float4 xv = *(const float4*)&xs[wave][nb][c];
                ax[nb] = fmaf(xv.x, wv0.x, ax[nb]); ay[nb] = fmaf(xv.x, wv0.y, ay[nb]);
                ax[nb] = fmaf(xv.y, wv1.x, ax[nb]); ay[nb] = fmaf(xv.y, wv1.y, ay[nb]);
                ax[nb] = fmaf(xv.z, wv2.x, ax[nb]); ay[nb] = fmaf(xv.z, wv2.y, ay[nb]);
                ax[nb] = fmaf(xv.w, wv3.x, ax[nb]); ay[nb] = fmaf(xv.w, wv3.y, ay[nb]);
            }
        }
        #pragma unroll
        for (int nb = 0; nb < MLP_NB; ++nb) {
            float a0 = fmaxf(ax[nb], 0.f), a1 = fmaxf(ay[nb], 0.f);
            float sm = a0 + a1;
            for (int m = 1; m < 64; m <<= 1) sm += __shfl_xor(sm, m, 64);
            float mu = sm * (1.f / 128.f);
            float d0 = a0 - mu, d1 = a1 - mu;
            float vv = d0 * d0 + d1 * d1;
            for (int m = 1; m < 64; m <<= 1) vv += __shfl_xor(vv, m, 64);
            float inv = rsqrtf(vv * (1.f / 128.f) + LN_EPS);
            float2 o;
            o.x = d0 * inv * gx + bex;
            o.y = d1 * inv * gy + bey;
            *(float2*)&h[(size_t)(base + nb) * HC + 2 * lane] = o;
            ushort2 o2; o2.x = f2bf(o.x); o2.y = f2bf(o.y);
            *(ushort2*)&h2[(size_t)(base + nb) * HC + 2 * lane] = o2;
        }
    }
}

// ---------------- fused layer: gather + mean + gating + mix + LN ----------------
// One wave per node, one node at a time (lean VGPR). LDS = 16 KB bf16-packed W
// + 4 KB hm = 20 KB -> 8 blocks/CU (32 waves) so the latency-bound gather keeps
// full TLP. W reads: Wpk[cp][k] puts lane k on bank k -> conflict-free (2-way
// across halves = free). h fp32 is self-read/self-written only (no race);
// h2 (gather source) ping-pongs between layers.

__global__ void __launch_bounds__(256) k_flayer(float* __restrict__ h,
        const ushort_t* __restrict__ h2in, ushort_t* __restrict__ h2out,
        const int* __restrict__ row_ptr, const int* __restrict__ col,
        const float* __restrict__ Wtm, const float* __restrict__ btm,
        const float* __restrict__ gall, const float* __restrict__ ball,
        float* __restrict__ tm, int layer) {
    __shared__ uint_t Wpk[128][CHN];     // 16 KB: packed bf16 pair (c=2cp hi, c=2cp+1 lo)
    __shared__ float hm[4][2][HC];       // 4 KB: [wave][h|m][c]
    int tid = threadIdx.x;
    for (int m = tid; m < 128 * CHN; m += 256) {
        int cp = m >> 5, k = m & 31;
        uint_t hi = (uint_t)f2bf(Wtm[(2 * cp) * CHN + k]) << 16;
        uint_t lo = (uint_t)f2bf(Wtm[(2 * cp + 1) * CHN + k]);
        Wpk[cp][k] = hi | lo;
    }
    __syncthreads();
    int wave = tid >> 6, lane = tid & 63;
    int k = lane & 31, half = lane >> 5;
    float bk  = btm[k];
    float gx  = gall[layer * HC + 2 * lane], gy  = gall[layer * HC + 2 * lane + 1];
    float bex = ball[layer * HC + 2 * lane], bey = ball[layer * HC + 2 * lane + 1];
    for (int node = blockIdx.x * 4 + wave; node < NN; node += gridDim.x * 4) {
        int r0 = row_ptr[node], r1 = row_ptr[node + 1];
        int deg = r1 - r0;
        // ---- gather-sum over in-neighbors (bf16 rows, fp32 accum) ----
        float ax = 0.f, ay = 0.f;
        for (int base = 0; base < deg; base += 64) {
            int nIdx = min(64, deg - base);
            int myc = (base + lane < deg) ? col[r0 + base + lane] : 0;
            int j = 0;
            for (; j + 4 <= nIdx; j += 4) {
                int s0 = __shfl(myc, j,     64);
                int s1 = __shfl(myc, j + 1, 64);
                int s2 = __shfl(myc, j + 2, 64);
                int s3 = __shfl(myc, j + 3, 64);
                ushort2 v0 = *(const ushort2*)&h2in[(size_t)s0 * HC + 2 * lane];
                ushort2 v1 = *(const ushort2*)&h2in[(size_t)s1 * HC + 2 * lane];
                ushort2 v2 = *(const ushort2*)&h2in[(size_t)s2 * HC + 2 * lane];
                ushort2 v3 = *(const ushort2*)&h2in[(size_t)s3 * HC + 2 * lane];
                ax += bf2f(v0.x); ay += bf2f(v0.y);
                ax += bf2f(v1.x); ay += bf2f(v1.y);
                ax += bf2f(v2.x); ay += bf2f(v2.y);
                ax += bf2f(v3.x); ay += bf2f(v3.y);
            }
            for (; j < nIdx; ++j) {
                int s = __shfl(myc, j, 64);
                ushort2 hv2 = *(const ushort2*)&h2in[(size_t)s * HC + 2 * lane];
                ax += bf2f(hv2.x); ay += bf2f(hv2.y);
            }
        }
        float2 hv = *(const float2*)&h[(size_t)node * HC + 2 * lane];
        float tmo = tm[(size_t)node * CHN + k];
        float invdeg = 1.f / (float)(deg + 1);
        float2 mv;
        mv.x = (ax + hv.x) * invdeg;
        mv.y = (ay + hv.y) * invdeg;
        *(float2*)&hm[wave][0][2 * lane] = hv;
        *(float2*)&hm[wave][1][2 * lane] = mv;
        // ---- z_k = [h|m] . W[:,k], halves split the 256-long K dim ----
        const float*  src  = hm[wave][half];
        const uint_t* wcol = &Wpk[half * 64][k];
        float z = 0.f;
        #pragma unroll 8
        for (int cp = 0; cp < 64; cp += 2) {
            float4 s = *(const float4*)&src[cp * 2];    // broadcast (uniform per half)
            uint_t w0 = wcol[cp * CHN];                 // bank k, conflict-free
            uint_t w1 = wcol[(cp + 1) * CHN];
            z = fmaf(s.x, bchi(w0), z);
            z = fmaf(s.y, bclo(w0), z);
            z = fmaf(s.z, bchi(w1), z);
            z = fmaf(s.w, bclo(w1), z);
        }
        z += __shfl_xor(z, 32, 64);      // combine halves
        z += bk;
        // ---- softmax over 32 gates (width-32: halves identical) ----
        float mx = z;
        for (int m = 1; m < 32; m <<= 1) mx = fmaxf(mx, __shfl_xor(mx, m, 32));
        float e = expf(z - mx);
        float se = e;
        for (int m = 1; m < 32; m <<= 1) se += __shfl_xor(se, m, 32);
        float p = e / se;
        // inclusive cumsum over gate index k
        float cum = p;
        for (int d = 1; d < 32; d <<= 1) {
            float t2 = __shfl_up(cum, d, 32);
            if (k >= d) cum += t2;
        }
        float raw = tmo + (1.f - tmo) * cum;
        if (half == 0) tm[(size_t)node * CHN + k] = raw;
        float sig = __shfl(raw, lane >> 1, 64);
        float v0 = hv.x * sig + mv.x * (1.f - sig);
        float v1 = hv.y * sig + mv.y * (1.f - sig);
        float sm = v0 + v1;
        for (int m = 1; m < 64; m <<= 1) sm += __shfl_xor(sm, m, 64);
        float mu = sm * (1.f / 128.f);
        float d0 = v0 - mu, d1 = v1 - mu;
        float vv = d0 * d0 + d1 * d1;
        for (int m = 1; m < 64; m <<= 1) vv += __shfl_xor(vv, m, 64);
        float inv = rsqrtf(vv * (1.f / 128.f) + LN_EPS);
        float2 o;
        o.x = d0 * inv * gx + bex;
        o.y = d1 * inv * gy + bey;
        *(float2*)&h[(size_t)node * HC + 2 * lane] = o;
        ushort2 o2; o2.x = f2bf(o.x); o2.y = f2bf(o.y);
        *(ushort2*)&h2out[(size_t)node * HC + 2 * lane] = o2;
    }
}

// ---------------- global mean pool (batch is sorted) ----------------

__global__ void __launch_bounds__(1024) k_pool(const float* __restrict__ h, const int* __restrict__ batch,
                                               float* __restrict__ out) {
    __shared__ float red[8][HC];
    int g = blockIdx.x;
    int tid = threadIdx.x;
    int c = tid & (HC - 1);
    int w = tid >> 7;          // 0..7 node-slice
    int a = 0, bnd = NN;
    while (a < bnd) { int mid = (a + bnd) >> 1; if (batch[mid] < g) a = mid + 1; else bnd = mid; }
    int start = a;
    bnd = NN;
    while (a < bnd) { int mid = (a + bnd) >> 1; if (batch[mid] <= g) a = mid + 1; else bnd = mid; }
    int end = a;
    float acc = 0.f;
    for (int n = start + w; n < end; n += 8) acc += h[(size_t)n * HC + c];
    red[w][c] = acc;
    __syncthreads();
    if (w == 0) {
        float s = red[0][c] + red[1][c] + red[2][c] + red[3][c]
                + red[4][c] + red[5][c] + red[6][c] + red[7][c];
        int count = end - start;
        out[g * HC + c] = s / (float)max(count, 1);
    }
}

// ---------------- launch ----------------

extern "C" void kernel_launch(void* const* d_in, const int* in_sizes, int n_in,
                              void* d_out, int out_size, void* d_ws, size_t ws_size,
                              hipStream_t stream) {
    const float* x     = (const float*)d_in[0];
    const int*   ei    = (const int*)d_in[1];
    const int*   batch = (const int*)d_in[2];
    const float* W_in  = (const float*)d_in[3];
    const float* b_in  = (const float*)d_in[4];
    const float* g_in  = (const float*)d_in[5];
    const float* be_in = (const float*)d_in[6];
    const float* W_tm  = (const float*)d_in[7];
    const float* b_tm  = (const float*)d_in[8];
    const float* tm_g  = (const float*)d_in[9];
    const float* tm_b  = (const float*)d_in[10];
    float* out = (float*)d_out;

    char* ws = (char*)d_ws;
    int*      cnt = (int*)(ws + 0);              // NN ints
    int*      fil = (int*)(ws + 200000);         // NN ints
    int*      rp  = (int*)(ws + 400000);         // NN+1 ints
    int*      col = (int*)(ws + 600004);         // NE ints   (ends at 3,000,004)
    float*    h   = (float*)(ws + 3000064);      // NN*HC fp32 (25.6 MB)
    ushort_t* h2A = (ushort_t*)(ws + 28600064);  // NN*HC bf16 (12.8 MB)
    ushort_t* h2B = (ushort_t*)(ws + 41400064);  // NN*HC bf16 (12.8 MB)
    float*    tm  = (float*)(ws + 54200064);     // NN*CHN fp32 (6.4 MB) -> 60,600,064
    int*      bsum = (int*)(ws + 60600064);      // SC_BLOCKS ints
    int*      boff = (int*)(ws + 60600320);      // SC_BLOCKS+1 ints

    hipMemsetAsync(cnt, 0, 400000, stream);       // cnt + fil (contiguous)
    hipMemsetAsync(tm, 0, 6400000, stream);       // last_tm_signal = 0

    k_hist<<<(NE + 255) / 256, 256, 0, stream>>>(ei, cnt);
    k_scanA<<<SC_BLOCKS, 256, 0, stream>>>(cnt, bsum);
    k_scanB<<<1, 64, 0, stream>>>(bsum, boff);
    k_scanC<<<SC_BLOCKS, 256, 0, stream>>>(cnt, boff, rp);
    k_fill<<<(NE + 255) / 256, 256, 0, stream>>>(ei, rp, fil, col);

    k_mlp<<<1563, 256, 0, stream>>>(x, W_in, b_in, g_in, be_in, h, h2A);

    k_flayer<<<2048, 256, 0, stream>>>(h, h2A, h2B, rp, col, W_tm, b_tm, tm_g, tm_b, tm, 0);
    k_flayer<<<2048, 256, 0, stream>>>(h, h2B, h2A, rp, col, W_tm, b_tm, tm_g, tm_b, tm, 1);
    k_flayer<<<2048, 256, 0, stream>>>(h, h2A, h2B, rp, col, W_tm, b_tm, tm_g, tm_b, tm, 2);

    k_pool<<<NG, 1024, 0, stream>>>(h, batch, out);
}